// Round 1
// baseline (428.924 us; speedup 1.0000x reference)
//
#include <hip/hip_runtime.h>
#include <hip/hip_bf16.h>

#define B_  4
#define S_  8192
#define H_  256
#define C_  128
#define NC_ 64
#define M_  (B_*S_)

static constexpr float LNG = -0.031748698f;  // ln(0.96875)

// ---------------- K1: QKV projection GEMM (M=32768, N=256, K=256) x3 ----------------
// 64x64 tile per block, 256 threads, 4x4 per thread, K-step 32, A transposed in LDS.
__global__ __launch_bounds__(256) void gemm_qkv(
    const float* __restrict__ X, const float* __restrict__ Wq,
    const float* __restrict__ Wk, const float* __restrict__ Wv,
    float* __restrict__ Qb, float* __restrict__ Kb, float* __restrict__ Vb)
{
  const int z = blockIdx.z;
  const float* __restrict__ W  = (z == 0) ? Wq : (z == 1) ? Wk : Wv;
  float* __restrict__       Ob = (z == 0) ? Qb : (z == 1) ? Kb : Vb;
  const int row0 = blockIdx.x * 64;
  const int col0 = blockIdx.y * 64;
  __shared__ float As[32][64];   // [k][row]
  __shared__ float Bs[32][64];   // [k][col]
  const int t  = threadIdx.x;
  const int ry = t >> 4, cx = t & 15;
  float acc[4][4] = {};
  for (int k0 = 0; k0 < H_; k0 += 32) {
    int f = t;
    #pragma unroll
    for (int rep = 0; rep < 2; ++rep, f += 256) {
      const int r  = f >> 3;             // 0..63
      const int kc = (f & 7) << 2;       // 0..28
      float4 v = *reinterpret_cast<const float4*>(&X[(size_t)(row0 + r) * H_ + k0 + kc]);
      As[kc + 0][r] = v.x; As[kc + 1][r] = v.y; As[kc + 2][r] = v.z; As[kc + 3][r] = v.w;
      const int kk = f >> 4;             // 0..31
      const int cc = (f & 15) << 2;      // 0..60
      float4 w = *reinterpret_cast<const float4*>(&W[(size_t)(k0 + kk) * H_ + col0 + cc]);
      *reinterpret_cast<float4*>(&Bs[kk][cc]) = w;
    }
    __syncthreads();
    #pragma unroll
    for (int kk = 0; kk < 32; ++kk) {
      float4 a = *reinterpret_cast<const float4*>(&As[kk][ry << 2]);
      float4 b = *reinterpret_cast<const float4*>(&Bs[kk][cx << 2]);
      const float av[4] = {a.x, a.y, a.z, a.w};
      const float bv[4] = {b.x, b.y, b.z, b.w};
      #pragma unroll
      for (int i = 0; i < 4; ++i)
        #pragma unroll
        for (int j = 0; j < 4; ++j)
          acc[i][j] = fmaf(av[i], bv[j], acc[i][j]);
    }
    __syncthreads();
  }
  #pragma unroll
  for (int i = 0; i < 4; ++i) {
    const int r = row0 + (ry << 2) + i;
    float4 v = make_float4(acc[i][0], acc[i][1], acc[i][2], acc[i][3]);
    *reinterpret_cast<float4*>(&Ob[(size_t)r * H_ + col0 + (cx << 2)]) = v;
  }
}

// ---------------- K2: RoPE (in-place on Q and K), torchtune interleaved pairs ----------
__global__ __launch_bounds__(256) void rope_kernel(float* __restrict__ Qb, float* __restrict__ Kb)
{
  const unsigned idx = blockIdx.x * 256u + threadIdx.x;   // 2 * M_ * 128 total
  float* __restrict__ buf = (idx >> 22) ? Kb : Qb;        // M_*128 = 2^22
  const unsigned id  = idx & 4194303u;
  const unsigned row = id >> 7;          // 0..M_-1
  const unsigned i   = id & 127u;        // pair index
  const unsigned s   = row & (S_ - 1);   // position
  // inv_freq = 10000^(-2i/256) = exp2(-i * (2/256)*log2(10000))
  const float invf = exp2f(-0.103810253f * (float)i);
  const float ang  = (float)s * invf;
  float sn, cs;
  sincosf(ang, &sn, &cs);
  float2 v = *reinterpret_cast<float2*>(&buf[(size_t)row * H_ + 2u * i]);
  float2 o;
  o.x = v.x * cs - v.y * sn;
  o.y = v.y * cs + v.x * sn;
  *reinterpret_cast<float2*>(&buf[(size_t)row * H_ + 2u * i]) = o;
}

// ---------------- K3: per-chunk decayed outer product T[b,c] = sum_m g^(C-1-m) K_m V_m^T ----
// Output 256x256 per (b,c); block computes 128x128 quadrant; 8x8 per thread.
__global__ __launch_bounds__(256) void chunk_outer(
    const float* __restrict__ Kb, const float* __restrict__ Vb, float* __restrict__ Tb)
{
  const int c  = blockIdx.x, b = blockIdx.y;
  const int i0 = (blockIdx.z >> 1) * 128;
  const int j0 = (blockIdx.z & 1) * 128;
  __shared__ float Ks[32][128];   // [m][i] pre-scaled by decay weight
  __shared__ float Vs[32][128];   // [m][j]
  const int t  = threadIdx.x;
  const int ry = t >> 4, cx = t & 15;
  const int r0 = ry << 3, c0 = cx << 3;
  const size_t rowbase = ((size_t)b * S_ + (size_t)c * C_) * H_;
  float acc[8][8] = {};
  for (int m0 = 0; m0 < C_; m0 += 32) {
    int f = t;
    #pragma unroll
    for (int rep = 0; rep < 4; ++rep, f += 256) {
      const int mm = f >> 5;
      const int jc = (f & 31) << 2;
      const float w = expf((float)(C_ - 1 - (m0 + mm)) * LNG);
      float4 kv = *reinterpret_cast<const float4*>(&Kb[rowbase + (size_t)(m0 + mm) * H_ + i0 + jc]);
      kv.x *= w; kv.y *= w; kv.z *= w; kv.w *= w;
      *reinterpret_cast<float4*>(&Ks[mm][jc]) = kv;
      *reinterpret_cast<float4*>(&Vs[mm][jc]) =
          *reinterpret_cast<const float4*>(&Vb[rowbase + (size_t)(m0 + mm) * H_ + j0 + jc]);
    }
    __syncthreads();
    #pragma unroll 8
    for (int mm = 0; mm < 32; ++mm) {
      float a[8], v[8];
      *(float4*)&a[0] = *(const float4*)&Ks[mm][r0];
      *(float4*)&a[4] = *(const float4*)&Ks[mm][r0 + 4];
      *(float4*)&v[0] = *(const float4*)&Vs[mm][c0];
      *(float4*)&v[4] = *(const float4*)&Vs[mm][c0 + 4];
      #pragma unroll
      for (int i = 0; i < 8; ++i)
        #pragma unroll
        for (int j = 0; j < 8; ++j)
          acc[i][j] = fmaf(a[i], v[j], acc[i][j]);
    }
    __syncthreads();
  }
  const size_t tb = (size_t)(b * NC_ + c) * (H_ * H_);
  #pragma unroll
  for (int i = 0; i < 8; ++i) {
    *reinterpret_cast<float4*>(&Tb[tb + (size_t)(i0 + r0 + i) * H_ + j0 + c0])     = *(float4*)&acc[i][0];
    *reinterpret_cast<float4*>(&Tb[tb + (size_t)(i0 + r0 + i) * H_ + j0 + c0 + 4]) = *(float4*)&acc[i][4];
  }
}

// ---------------- K4: in-place exclusive scan over chunks: S[c] = g^C S[c-1] + T[c-1] -----
__global__ __launch_bounds__(256) void scan_kernel(float* __restrict__ Tb)
{
  const unsigned e  = blockIdx.x * 256u + threadIdx.x;  // B_*65536 threads
  const unsigned b  = e >> 16;
  const unsigned el = e & 65535u;
  const float gC = expf((float)C_ * LNG);  // gamma^128
  float run = 0.f;
  size_t p = (size_t)b * NC_ * 65536u + el;
  for (int c = 0; c < NC_; ++c, p += 65536u) {
    const float tv = Tb[p];
    Tb[p] = run;               // exclusive: state entering chunk c
    run = fmaf(gC, run, tv);
  }
}

// ---------------- K5: per-chunk output: local masked attn + cross Q@Sstate ---------------
// block = (b,c): scores 128x128 -> ScT in LDS; out = ScT^T... ScT[m][n] used as A^T.
__global__ __launch_bounds__(256) void retention_out(
    const float* __restrict__ Qb, const float* __restrict__ Kb,
    const float* __restrict__ Vb, const float* __restrict__ Sb,
    float* __restrict__ Out)
{
  const int c = blockIdx.x, b = blockIdx.y;
  __shared__ float ScT[C_][C_];   // [m][n] masked+decayed scores (64 KB)
  __shared__ float StA[32][C_];   // [k][n] transposed Q staging
  __shared__ float StB[32][C_];   // [k][m]/[m][j]/[k][j] staging
  const int t  = threadIdx.x;
  const int ry = t >> 4, cx = t & 15;
  const int r0 = ry << 3, c0 = cx << 3;
  const size_t rowbase = ((size_t)b * S_ + (size_t)c * C_) * H_;

  // ---- phase 1: Sc[n][m] = Q_n . K_m over d=256 ----
  {
    float acc[8][8] = {};
    for (int k0 = 0; k0 < H_; k0 += 32) {
      int f = t;
      #pragma unroll
      for (int rep = 0; rep < 4; ++rep, f += 256) {
        const int n  = f >> 3;
        const int kc = (f & 7) << 2;
        float4 q = *reinterpret_cast<const float4*>(&Qb[rowbase + (size_t)n * H_ + k0 + kc]);
        StA[kc + 0][n] = q.x; StA[kc + 1][n] = q.y; StA[kc + 2][n] = q.z; StA[kc + 3][n] = q.w;
        float4 k = *reinterpret_cast<const float4*>(&Kb[rowbase + (size_t)n * H_ + k0 + kc]);
        StB[kc + 0][n] = k.x; StB[kc + 1][n] = k.y; StB[kc + 2][n] = k.z; StB[kc + 3][n] = k.w;
      }
      __syncthreads();
      #pragma unroll 8
      for (int kk = 0; kk < 32; ++kk) {
        float a[8], bb[8];
        *(float4*)&a[0]  = *(const float4*)&StA[kk][r0];
        *(float4*)&a[4]  = *(const float4*)&StA[kk][r0 + 4];
        *(float4*)&bb[0] = *(const float4*)&StB[kk][c0];
        *(float4*)&bb[4] = *(const float4*)&StB[kk][c0 + 4];
        #pragma unroll
        for (int i = 0; i < 8; ++i)
          #pragma unroll
          for (int j = 0; j < 8; ++j)
            acc[i][j] = fmaf(a[i], bb[j], acc[i][j]);
      }
      __syncthreads();
    }
    // mask + decay, store transposed [m][n]
    #pragma unroll
    for (int i = 0; i < 8; ++i)
      #pragma unroll
      for (int j = 0; j < 8; ++j) {
        const int n = r0 + i, m = c0 + j;
        ScT[m][n] = (n >= m) ? acc[i][j] * expf((float)(n - m) * LNG) : 0.f;
      }
  }
  __syncthreads();

  // ---- phase 2: out[n][j] = sum_m ScT[m][n] V[m][j] + g^(n+1) sum_k Q[n][k] Sstate[k][j]
  const size_t sbase = (size_t)(b * NC_ + c) * (H_ * H_);
  for (int h = 0; h < 2; ++h) {
    const int j0 = h * 128;
    float accL[8][8] = {};
    float accC[8][8] = {};
    // local part (k-dim = 128 chunk rows)
    for (int m0 = 0; m0 < C_; m0 += 32) {
      int f = t;
      #pragma unroll
      for (int rep = 0; rep < 4; ++rep, f += 256) {
        const int mm = f >> 5;
        const int jc = (f & 31) << 2;
        *reinterpret_cast<float4*>(&StB[mm][jc]) =
            *reinterpret_cast<const float4*>(&Vb[rowbase + (size_t)(m0 + mm) * H_ + j0 + jc]);
      }
      __syncthreads();
      #pragma unroll 8
      for (int mm = 0; mm < 32; ++mm) {
        float a[8], v[8];
        *(float4*)&a[0] = *(const float4*)&ScT[m0 + mm][r0];
        *(float4*)&a[4] = *(const float4*)&ScT[m0 + mm][r0 + 4];
        *(float4*)&v[0] = *(const float4*)&StB[mm][c0];
        *(float4*)&v[4] = *(const float4*)&StB[mm][c0 + 4];
        #pragma unroll
        for (int i = 0; i < 8; ++i)
          #pragma unroll
          for (int j = 0; j < 8; ++j)
            accL[i][j] = fmaf(a[i], v[j], accL[i][j]);
      }
      __syncthreads();
    }
    // cross part (k-dim = 256)
    for (int k0 = 0; k0 < H_; k0 += 32) {
      int f = t;
      #pragma unroll
      for (int rep = 0; rep < 4; ++rep, f += 256) {
        const int n  = f >> 3;
        const int kc = (f & 7) << 2;
        float4 q = *reinterpret_cast<const float4*>(&Qb[rowbase + (size_t)n * H_ + k0 + kc]);
        StA[kc + 0][n] = q.x; StA[kc + 1][n] = q.y; StA[kc + 2][n] = q.z; StA[kc + 3][n] = q.w;
        const int kk = f >> 5;
        const int jc = (f & 31) << 2;
        *reinterpret_cast<float4*>(&StB[kk][jc]) =
            *reinterpret_cast<const float4*>(&Sb[sbase + (size_t)(k0 + kk) * H_ + j0 + jc]);
      }
      __syncthreads();
      #pragma unroll 8
      for (int kk = 0; kk < 32; ++kk) {
        float a[8], s[8];
        *(float4*)&a[0] = *(const float4*)&StA[kk][r0];
        *(float4*)&a[4] = *(const float4*)&StA[kk][r0 + 4];
        *(float4*)&s[0] = *(const float4*)&StB[kk][c0];
        *(float4*)&s[4] = *(const float4*)&StB[kk][c0 + 4];
        #pragma unroll
        for (int i = 0; i < 8; ++i)
          #pragma unroll
          for (int j = 0; j < 8; ++j)
            accC[i][j] = fmaf(a[i], s[j], accC[i][j]);
      }
      __syncthreads();
    }
    // epilogue: cross term scaled by gamma^(n_local+1)
    #pragma unroll
    for (int i = 0; i < 8; ++i) {
      const int n = r0 + i;
      const float g = expf((float)(n + 1) * LNG);
      float o[8];
      #pragma unroll
      for (int j = 0; j < 8; ++j) o[j] = fmaf(g, accC[i][j], accL[i][j]);
      *reinterpret_cast<float4*>(&Out[rowbase + (size_t)n * H_ + j0 + c0])     = *(float4*)&o[0];
      *reinterpret_cast<float4*>(&Out[rowbase + (size_t)n * H_ + j0 + c0 + 4]) = *(float4*)&o[4];
    }
  }
}

extern "C" void kernel_launch(void* const* d_in, const int* in_sizes, int n_in,
                              void* d_out, int out_size, void* d_ws, size_t ws_size,
                              hipStream_t stream) {
  const float* X  = (const float*)d_in[0];
  const float* Wq = (const float*)d_in[1];
  const float* Wk = (const float*)d_in[2];
  const float* Wv = (const float*)d_in[3];
  float* Out = (float*)d_out;
  float* ws  = (float*)d_ws;
  // workspace layout (floats): Q | K | V | T/Sstate  -> 3*8.39M + 16.78M = 41.9M floats (168 MB)
  float* Qb = ws;
  float* Kb = Qb + (size_t)M_ * H_;
  float* Vb = Kb + (size_t)M_ * H_;
  float* Tb = Vb + (size_t)M_ * H_;

  dim3 g1(M_ / 64, H_ / 64, 3);
  gemm_qkv<<<g1, 256, 0, stream>>>(X, Wq, Wk, Wv, Qb, Kb, Vb);

  rope_kernel<<<(2u * M_ * (H_ / 2)) / 256, 256, 0, stream>>>(Qb, Kb);

  dim3 g3(NC_, B_, 4);
  chunk_outer<<<g3, 256, 0, stream>>>(Kb, Vb, Tb);

  scan_kernel<<<(B_ * H_ * H_) / 256, 256, 0, stream>>>(Tb);

  dim3 g5(NC_, B_);
  retention_out<<<g5, 256, 0, stream>>>(Qb, Kb, Vb, Tb, Out);
}

// Round 2
// 300.189 us; speedup vs baseline: 1.4288x; 1.4288x over previous
//
#include <hip/hip_runtime.h>
#include <hip/hip_bf16.h>

#define B_  4
#define S_  8192
#define H_  256
#define C_  128
#define NC_ 64
#define M_  (B_*S_)

typedef unsigned short u16;
typedef __attribute__((ext_vector_type(8))) short short8;
typedef __attribute__((ext_vector_type(4))) float f32x4;

static constexpr float LNG   = -0.031748698f;          // ln(0.96875)
static constexpr float INVG  = 1.0322580645161290f;    // 1/0.96875
static constexpr float ROPE2 = -0.103810253f;          // -(2/256)*log2(10000)

__device__ __forceinline__ u16 f2b(float x) {
  union { __hip_bfloat16 b; u16 u; } c; c.b = __float2bfloat16(x); return c.u;
}
__device__ __forceinline__ float b2f(u16 u) {
  union { u16 u; __hip_bfloat16 b; } c; c.u = u; return __bfloat162float(c.b);
}
__device__ __forceinline__ f32x4 mfma16(short8 a, short8 b, f32x4 c) {
  return __builtin_amdgcn_mfma_f32_16x16x32_bf16(a, b, c, 0, 0, 0);
}

// ---- LDS tile helpers: [128 rows][64 cols] bf16, 128B rows, XOR swizzle ----
// phys_slot = logical_slot ^ (row & 7)   (slots are 16B units, 8 per row)
__device__ __forceinline__ void stageB(const u16* __restrict__ src, int stride,
                                       u16* lds, int t) {
  #pragma unroll
  for (int it = 0; it < 4; ++it) {
    const int u = it*256 + t, row = u >> 3, sl = u & 7, lsl = sl ^ (row & 7);
    uint4 v = *reinterpret_cast<const uint4*>(src + (size_t)row*stride + lsl*8);
    *reinterpret_cast<uint4*>(lds + u*8) = v;
  }
}
__device__ __forceinline__ void stageF(const float* __restrict__ src, int stride,
                                       u16* lds, int t) {
  #pragma unroll
  for (int it = 0; it < 4; ++it) {
    const int u = it*256 + t, row = u >> 3, sl = u & 7, lsl = sl ^ (row & 7);
    const float* p = src + (size_t)row*stride + lsl*8;
    float4 a = *reinterpret_cast<const float4*>(p);
    float4 b = *reinterpret_cast<const float4*>(p + 4);
    u16 o[8] = {f2b(a.x), f2b(a.y), f2b(a.z), f2b(a.w),
                f2b(b.x), f2b(b.y), f2b(b.z), f2b(b.w)};
    *reinterpret_cast<uint4*>(lds + u*8) = *reinterpret_cast<uint4*>(o);
  }
}
__device__ __forceinline__ short8 fragr(const u16* lds, int row, int slot) {
  return *reinterpret_cast<const short8*>(lds + row*64 + ((slot ^ (row & 7)) << 3));
}

// ---------------- K0: transpose weights to [z][n][k] bf16 ----------------
__global__ __launch_bounds__(256) void convert_w(const float* __restrict__ Wq,
                                                 const float* __restrict__ Wk,
                                                 const float* __restrict__ Wv,
                                                 u16* __restrict__ WhT) {
  const int t2 = blockIdx.x*256 + threadIdx.x;          // 0..24575
  const int z = t2 >> 13, r = t2 & 8191;
  const int n = r >> 5, k0 = (r & 31) << 3;
  const float* W = (z == 0) ? Wq : (z == 1) ? Wk : Wv;
  u16 o[8];
  #pragma unroll
  for (int j = 0; j < 8; ++j) o[j] = f2b(W[(size_t)(k0 + j)*H_ + n]);
  *reinterpret_cast<uint4*>(WhT + ((size_t)z << 16) + n*H_ + k0) =
      *reinterpret_cast<uint4*>(o);
}

// ---------------- K1: fused QKV projection + RoPE + transposes ----------------
// z=0: Qh row-major. z=1: Kh row-major + KT[b][d][s]. z=2: VT[b][j][s] + VTw (decay-weighted).
__global__ __launch_bounds__(256) void gemm_qkv(
    const float* __restrict__ X, const u16* __restrict__ WhT,
    u16* __restrict__ Qh, u16* __restrict__ Kh,
    u16* __restrict__ KT, u16* __restrict__ VT, u16* __restrict__ VTw)
{
  __shared__ u16 SM[16384];    // 32KB: As [0,8192), Bs [8192,16384)
  const int t = threadIdx.x, l = t & 63, wid = t >> 6;
  const int wr = wid >> 1, wc = wid & 1, g = l >> 4, l15 = l & 15;
  const int z = blockIdx.z;
  const int row0 = blockIdx.x * 128, col0 = blockIdx.y * 128;
  u16* As = SM; u16* Bs = SM + 8192;
  const u16* Wz = WhT + ((size_t)z << 16);
  f32x4 acc[4][4] = {};

  for (int ks = 0; ks < 4; ++ks) {
    stageF(X + (size_t)row0*H_ + ks*64, H_, As, t);
    stageB(Wz + (size_t)col0*H_ + ks*64, H_, Bs, t);
    __syncthreads();
    #pragma unroll
    for (int kb = 0; kb < 2; ++kb) {
      short8 a[4], b[4];
      #pragma unroll
      for (int i = 0; i < 4; ++i) a[i] = fragr(As, wr*64 + i*16 + l15, kb*4 + g);
      #pragma unroll
      for (int j = 0; j < 4; ++j) b[j] = fragr(Bs, wc*64 + j*16 + l15, kb*4 + g);
      #pragma unroll
      for (int i = 0; i < 4; ++i)
        #pragma unroll
        for (int j = 0; j < 4; ++j)
          acc[i][j] = mfma16(a[i], b[j], acc[i][j]);
    }
    __syncthreads();
  }

  // ---- epilogue: rope (z<2), row-major store (z<2), LDS transpose (z>=1) ----
  const int cbase = col0 + wc*64;
  #pragma unroll
  for (int jb = 0; jb < 4; ++jb) {
    const int cg = cbase + jb*16 + l15;
    const float invf = exp2f(ROPE2 * (float)(cg >> 1));
    #pragma unroll
    for (int ib = 0; ib < 4; ++ib) {
      const int rl0 = ib*16 + g*4;
      float o4[4];
      #pragma unroll
      for (int r = 0; r < 4; ++r) {
        const float v = acc[ib][jb][r];
        if (z < 2) {
          const float p = __shfl_xor(v, 1);
          float snv, csv;
          sincosf((float)((row0 + wr*64 + rl0 + r) & (S_-1)) * invf, &snv, &csv);
          o4[r] = (l & 1) ? fmaf(v, csv, p*snv) : fmaf(v, csv, -(p*snv));
        } else {
          o4[r] = v;
        }
      }
      if (z < 2) {  // packed row-major store (even lanes write pair)
        u16* Ob = z ? Kh : Qh;
        #pragma unroll
        for (int r = 0; r < 4; ++r) {
          const float pv = __shfl_xor(o4[r], 1);
          if (!(l & 1)) {
            const unsigned w32 = (unsigned)f2b(o4[r]) | ((unsigned)f2b(pv) << 16);
            *reinterpret_cast<unsigned*>(Ob + (size_t)(row0 + wr*64 + rl0 + r)*H_ + cg) = w32;
          }
        }
      }
      if (z >= 1) {  // transpose region: [cl 64][rl 64] bf16, swizzled
        u16* R = SM + wid*4096;
        const int cl = jb*16 + l15;
        ushort4 pk;
        pk.x = f2b(o4[0]); pk.y = f2b(o4[1]); pk.z = f2b(o4[2]); pk.w = f2b(o4[3]);
        *reinterpret_cast<ushort4*>(R + cl*64 + (rl0 ^ ((cl & 7) << 3))) = pk;
      }
    }
  }

  if (z >= 1) {
    __syncthreads();
    // coalesced readback: 2048 16B units over 4 wave regions
    #pragma unroll
    for (int it = 0; it < 8; ++it) {
      const int u = it*256 + t;
      const int w = u >> 9, cl = (u >> 3) & 63, sl = u & 7;
      const int sp = sl ^ (cl & 7);
      uint4 v = *reinterpret_cast<const uint4*>(SM + w*4096 + cl*64 + sp*8);
      const int dg  = col0 + (w & 1)*64 + cl;
      const int rg0 = row0 + ((w >> 1))*64 + sl*8;
      const int bb = rg0 >> 13, s0 = rg0 & (S_-1);
      const size_t dst = ((size_t)(bb*H_ + dg) << 13) + s0;
      if (z == 1) {
        *reinterpret_cast<uint4*>(KT + dst) = v;
      } else {
        *reinterpret_cast<uint4*>(VT + dst) = v;
        const u16* pv = reinterpret_cast<const u16*>(&v);
        float wv = expf((float)(C_ - 1 - (s0 & (C_-1))) * LNG);
        u16 ow[8];
        #pragma unroll
        for (int j2 = 0; j2 < 8; ++j2) { ow[j2] = f2b(b2f(pv[j2]) * wv); wv *= INVG; }
        *reinterpret_cast<uint4*>(VTw + dst) = *reinterpret_cast<uint4*>(ow);
      }
    }
  }
}

// ---------------- K2: chunk outer product Tt[b,c][j][i] = sum_m w(m) V[m][j] K[m][i] ----
__global__ __launch_bounds__(256) void chunk_outer(
    const u16* __restrict__ KT, const u16* __restrict__ VTw, u16* __restrict__ Tt)
{
  __shared__ u16 SM[16384];
  const int t = threadIdx.x, l = t & 63, wid = t >> 6;
  const int wr = wid >> 1, wc = wid & 1, g = l >> 4, l15 = l & 15;
  const int c = blockIdx.x, b = blockIdx.y, q = blockIdx.z;
  const int j0 = (q >> 1) * 128, i0 = (q & 1) * 128;
  u16* As = SM; u16* Bs = SM + 8192;
  f32x4 acc[4][4] = {};

  for (int ks = 0; ks < 2; ++ks) {
    stageB(VTw + ((size_t)(b*H_ + j0) << 13) + c*C_ + ks*64, S_, As, t);
    stageB(KT  + ((size_t)(b*H_ + i0) << 13) + c*C_ + ks*64, S_, Bs, t);
    __syncthreads();
    #pragma unroll
    for (int kb = 0; kb < 2; ++kb) {
      short8 a[4], bb[4];
      #pragma unroll
      for (int i = 0; i < 4; ++i) a[i] = fragr(As, wr*64 + i*16 + l15, kb*4 + g);
      #pragma unroll
      for (int j = 0; j < 4; ++j) bb[j] = fragr(Bs, wc*64 + j*16 + l15, kb*4 + g);
      #pragma unroll
      for (int i = 0; i < 4; ++i)
        #pragma unroll
        for (int j = 0; j < 4; ++j)
          acc[i][j] = mfma16(a[i], bb[j], acc[i][j]);
    }
    __syncthreads();
  }
  const size_t tb = ((size_t)(b*NC_ + c)) << 16;
  #pragma unroll
  for (int jb = 0; jb < 4; ++jb) {
    const int i = i0 + wc*64 + jb*16 + l15;
    #pragma unroll
    for (int ib = 0; ib < 4; ++ib) {
      #pragma unroll
      for (int r = 0; r < 4; ++r) {
        const int j = j0 + wr*64 + ib*16 + g*4 + r;
        Tt[tb + (size_t)j*H_ + i] = f2b(acc[ib][jb][r]);
      }
    }
  }
}

// ---------------- K3: in-place exclusive scan: state[c] = g^C state[c-1] + T[c-1] ----
__global__ __launch_bounds__(256) void scan_state(u16* __restrict__ Tt)
{
  const unsigned e = blockIdx.x*256u + threadIdx.x;   // B_*65536 threads
  const unsigned b = e >> 16, el = e & 65535u;
  const float gC = expf((float)C_ * LNG);
  float run = 0.f;
  size_t p = (((size_t)b * NC_) << 16) + el;
  for (int c = 0; c < NC_; ++c, p += 65536) {
    const float tv = b2f(Tt[p]);
    Tt[p] = f2b(run);
    run = fmaf(gC, run, tv);
  }
}

// ---------------- K4: per-chunk output via MFMA ----------------
__global__ __launch_bounds__(256) void retention_out(
    const u16* __restrict__ Qh, const u16* __restrict__ Kh,
    const u16* __restrict__ VT, const u16* __restrict__ Tt,
    float* __restrict__ Out)
{
  __shared__ u16 SM[32768];   // 64KB: Sc [0,16384) u16, StA [16384,24576), StB [24576,32768)
  const int t = threadIdx.x, l = t & 63, wid = t >> 6;
  const int g = l >> 4, l15 = l & 15;
  const int c = blockIdx.x, b = blockIdx.y;
  u16* Sc = SM; u16* StA = SM + 16384; u16* StB = SM + 24576;
  const size_t chunkrow = ((size_t)(b*S_ + c*C_)) << 8;   // * H_

  // ---- phase 1: St[m][n] = sum_d K[m,d] Q[n,d]; mask+decay -> Sc[n][m] (swizzled) ----
  {
    const int m0w = (wid >> 1)*64, n0w = (wid & 1)*64;
    f32x4 acc[4][4] = {};
    for (int ks = 0; ks < 4; ++ks) {
      stageB(Kh + chunkrow + ks*64, H_, StA, t);
      stageB(Qh + chunkrow + ks*64, H_, StB, t);
      __syncthreads();
      #pragma unroll
      for (int kb = 0; kb < 2; ++kb) {
        short8 a[4], bb[4];
        #pragma unroll
        for (int i = 0; i < 4; ++i) a[i] = fragr(StA, m0w + i*16 + l15, kb*4 + g);
        #pragma unroll
        for (int j = 0; j < 4; ++j) bb[j] = fragr(StB, n0w + j*16 + l15, kb*4 + g);
        #pragma unroll
        for (int i = 0; i < 4; ++i)
          #pragma unroll
          for (int j = 0; j < 4; ++j)
            acc[i][j] = mfma16(a[i], bb[j], acc[i][j]);
      }
      __syncthreads();
    }
    #pragma unroll
    for (int jb = 0; jb < 4; ++jb) {
      const int n = n0w + jb*16 + l15;
      #pragma unroll
      for (int ib = 0; ib < 4; ++ib) {
        const int m0 = m0w + ib*16 + g*4;
        ushort4 pk;
        #pragma unroll
        for (int r = 0; r < 4; ++r) {
          const int m = m0 + r;
          const float sv = (n >= m) ? acc[ib][jb][r] * expf((float)(n - m)*LNG) : 0.f;
          reinterpret_cast<u16*>(&pk)[r] = f2b(sv);
        }
        *reinterpret_cast<ushort4*>(Sc + n*128 + (m0 ^ ((n & 15) << 3))) = pk;
      }
    }
  }
  __syncthreads();

  // ---- phase 2: D[j][n] = gamma^(n+1) * (Q @ state)^T + (S V)^T ----
  const int j0w = (wid >> 1)*64, n0w = (wid & 1)*64;
  const size_t sbase = ((size_t)(b*NC_ + c)) << 16;
  for (int h = 0; h < 2; ++h) {
    f32x4 acc[4][4] = {};
    // cross: contraction over d (4 ksteps)
    for (int ks = 0; ks < 4; ++ks) {
      stageB(Tt + sbase + (size_t)(h*128)*H_ + ks*64, H_, StA, t);
      stageB(Qh + chunkrow + ks*64, H_, StB, t);
      __syncthreads();
      #pragma unroll
      for (int kb = 0; kb < 2; ++kb) {
        short8 a[4], bb[4];
        #pragma unroll
        for (int i = 0; i < 4; ++i) a[i] = fragr(StA, j0w + i*16 + l15, kb*4 + g);
        #pragma unroll
        for (int j = 0; j < 4; ++j) bb[j] = fragr(StB, n0w + j*16 + l15, kb*4 + g);
        #pragma unroll
        for (int i = 0; i < 4; ++i)
          #pragma unroll
          for (int j = 0; j < 4; ++j)
            acc[i][j] = mfma16(a[i], bb[j], acc[i][j]);
      }
      __syncthreads();
    }
    // scale cross by gamma^(n+1)
    #pragma unroll
    for (int jb = 0; jb < 4; ++jb) {
      const float gn = expf((float)(n0w + jb*16 + l15 + 1) * LNG);
      #pragma unroll
      for (int ib = 0; ib < 4; ++ib)
        #pragma unroll
        for (int r = 0; r < 4; ++r) acc[ib][jb][r] *= gn;
    }
    // local: contraction over m (2 ksteps), B from Sc
    for (int ks2 = 0; ks2 < 2; ++ks2) {
      stageB(VT + ((size_t)(b*H_ + h*128) << 13) + c*C_ + ks2*64, S_, StA, t);
      __syncthreads();
      #pragma unroll
      for (int kb = 0; kb < 2; ++kb) {
        short8 a[4], bb[4];
        #pragma unroll
        for (int i = 0; i < 4; ++i) a[i] = fragr(StA, j0w + i*16 + l15, kb*4 + g);
        #pragma unroll
        for (int j = 0; j < 4; ++j) {
          const int n = n0w + j*16 + l15;
          bb[j] = *reinterpret_cast<const short8*>(
              Sc + n*128 + (((ks2*8 + kb*4 + g) ^ (n & 15)) << 3));
        }
        #pragma unroll
        for (int i = 0; i < 4; ++i)
          #pragma unroll
          for (int j = 0; j < 4; ++j)
            acc[i][j] = mfma16(a[i], bb[j], acc[i][j]);
      }
      __syncthreads();
    }
    // epilogue: restage [64 n][128 j] f32 in LDS (swizzled), coalesced global store
    float* OL = reinterpret_cast<float*>(SM + 16384);   // 32KB region
    for (int ph = 0; ph < 2; ++ph) {
      if ((wid & 1) == ph) {
        #pragma unroll
        for (int jb = 0; jb < 4; ++jb) {
          const int nl = jb*16 + l15;
          #pragma unroll
          for (int ib = 0; ib < 4; ++ib) {
            const int jl = j0w + ib*16 + g*4;
            *reinterpret_cast<f32x4*>(OL + nl*128 + (jl ^ ((nl & 15) << 2))) = acc[ib][jb];
          }
        }
      }
      __syncthreads();
      #pragma unroll
      for (int it = 0; it < 8; ++it) {
        const int u = it*256 + t;
        const int nl = u >> 5, sl = u & 31;
        f32x4 v = *reinterpret_cast<const f32x4*>(OL + nl*128 + ((sl ^ (nl & 15)) << 2));
        const int n = c*C_ + ph*64 + nl;
        *reinterpret_cast<f32x4*>(Out + (((size_t)(b*S_ + n)) << 8) + h*128 + sl*4) = v;
      }
      __syncthreads();
    }
  }
}

extern "C" void kernel_launch(void* const* d_in, const int* in_sizes, int n_in,
                              void* d_out, int out_size, void* d_ws, size_t ws_size,
                              hipStream_t stream) {
  const float* X  = (const float*)d_in[0];
  const float* Wq = (const float*)d_in[1];
  const float* Wk = (const float*)d_in[2];
  const float* Wv = (const float*)d_in[3];
  float* Out = (float*)d_out;
  u16* ws = (u16*)d_ws;
  // workspace (u16 elems): WhT 196608 | Qh,Kh,KT,VT,VTw 8388608 each | Tt 16777216  (~118 MB)
  u16* WhT = ws;
  u16* Qh  = WhT + 196608;
  u16* Kh  = Qh  + (size_t)M_*H_;
  u16* KT  = Kh  + (size_t)M_*H_;
  u16* VT  = KT  + (size_t)M_*H_;
  u16* VTw = VT  + (size_t)M_*H_;
  u16* Tt  = VTw + (size_t)M_*H_;

  convert_w<<<96, 256, 0, stream>>>(Wq, Wk, Wv, WhT);
  gemm_qkv<<<dim3(M_/128, H_/128, 3), 256, 0, stream>>>(X, WhT, Qh, Kh, KT, VT, VTw);
  chunk_outer<<<dim3(NC_, B_, 4), 256, 0, stream>>>(KT, VTw, Tt);
  scan_state<<<(B_*H_*H_)/256, 256, 0, stream>>>(Tt);
  retention_out<<<dim3(NC_, B_), 256, 0, stream>>>(Qh, Kh, VT, Tt, Out);
}

// Round 3
// 134.658 us; speedup vs baseline: 3.1853x; 2.2293x over previous
//
#include <hip/hip_runtime.h>
#include <hip/hip_bf16.h>

#define B_  4
#define S_  8192
#define H_  256
#define C_  128
#define NC_ 64
#define M_  (B_*S_)

typedef unsigned short u16;
typedef __attribute__((ext_vector_type(8))) short short8;
typedef __attribute__((ext_vector_type(4))) float f32x4;

static constexpr float LNG   = -0.031748698f;          // ln(0.96875)
static constexpr float INVG  = 1.0322580645161290f;    // 1/0.96875
static constexpr float ROPE2 = -0.103810253f;          // -(2/256)*log2(10000)

__device__ __forceinline__ u16 f2b(float x) {
  union { __hip_bfloat16 b; u16 u; } c; c.b = __float2bfloat16(x); return c.u;
}
__device__ __forceinline__ float b2f(u16 u) {
  union { u16 u; __hip_bfloat16 b; } c; c.u = u; return __bfloat162float(c.b);
}
__device__ __forceinline__ f32x4 mfma16(short8 a, short8 b, f32x4 c) {
  return __builtin_amdgcn_mfma_f32_16x16x32_bf16(a, b, c, 0, 0, 0);
}

// ---- LDS tile helpers: [128 rows][64 cols] bf16, 128B rows, XOR swizzle ----
// phys_slot = logical_slot ^ (row & 7)   (slots are 16B units, 8 per row)
__device__ __forceinline__ void stageB(const u16* __restrict__ src, int stride,
                                       u16* lds, int t) {
  #pragma unroll
  for (int it = 0; it < 4; ++it) {
    const int u = it*256 + t, row = u >> 3, sl = u & 7, lsl = sl ^ (row & 7);
    uint4 v = *reinterpret_cast<const uint4*>(src + (size_t)row*stride + lsl*8);
    *reinterpret_cast<uint4*>(lds + u*8) = v;
  }
}
__device__ __forceinline__ void stageF(const float* __restrict__ src, int stride,
                                       u16* lds, int t) {
  #pragma unroll
  for (int it = 0; it < 4; ++it) {
    const int u = it*256 + t, row = u >> 3, sl = u & 7, lsl = sl ^ (row & 7);
    const float* p = src + (size_t)row*stride + lsl*8;
    float4 a = *reinterpret_cast<const float4*>(p);
    float4 b = *reinterpret_cast<const float4*>(p + 4);
    u16 o[8] = {f2b(a.x), f2b(a.y), f2b(a.z), f2b(a.w),
                f2b(b.x), f2b(b.y), f2b(b.z), f2b(b.w)};
    *reinterpret_cast<uint4*>(lds + u*8) = *reinterpret_cast<uint4*>(o);
  }
}
__device__ __forceinline__ short8 fragr(const u16* lds, int row, int slot) {
  return *reinterpret_cast<const short8*>(lds + row*64 + ((slot ^ (row & 7)) << 3));
}

// ---------------- K0: transpose weights to [z][n][k] bf16 ----------------
__global__ __launch_bounds__(256) void convert_w(const float* __restrict__ Wq,
                                                 const float* __restrict__ Wk,
                                                 const float* __restrict__ Wv,
                                                 u16* __restrict__ WhT) {
  const int t2 = blockIdx.x*256 + threadIdx.x;          // 0..24575
  const int z = t2 >> 13, r = t2 & 8191;
  const int n = r >> 5, k0 = (r & 31) << 3;
  const float* W = (z == 0) ? Wq : (z == 1) ? Wk : Wv;
  u16 o[8];
  #pragma unroll
  for (int j = 0; j < 8; ++j) o[j] = f2b(W[(size_t)(k0 + j)*H_ + n]);
  *reinterpret_cast<uint4*>(WhT + ((size_t)z << 16) + n*H_ + k0) =
      *reinterpret_cast<uint4*>(o);
}

// ---------------- K1: fused QKV projection + RoPE + transposes ----------------
// z=0: Qh row-major (swapped mfma). z=1: Kh row-major + KT[b][d][s] (swapped mfma).
// z=2: VT[b][j][s] + VTw decay-weighted (normal mfma, per-wave transpose regions).
__global__ __launch_bounds__(256) void gemm_qkv(
    const float* __restrict__ X, const u16* __restrict__ WhT,
    u16* __restrict__ Qh, u16* __restrict__ Kh,
    u16* __restrict__ KT, u16* __restrict__ VT, u16* __restrict__ VTw)
{
  __shared__ u16 SM[16384];    // 32KB: As [0,8192), Bs [8192,16384); reused by epilogue
  const int t = threadIdx.x, l = t & 63, wid = t >> 6;
  const int wr = wid >> 1, wc = wid & 1, g = l >> 4, l15 = l & 15;
  const int z = blockIdx.z;
  const int row0 = blockIdx.x * 128, col0 = blockIdx.y * 128;
  u16* As = SM; u16* Bs = SM + 8192;
  const u16* Wz = WhT + ((size_t)z << 16);
  f32x4 acc[4][4] = {};

  for (int ks = 0; ks < 4; ++ks) {
    stageF(X + (size_t)row0*H_ + ks*64, H_, As, t);
    stageB(Wz + (size_t)col0*H_ + ks*64, H_, Bs, t);
    __syncthreads();
    if (z < 2) {
      // swapped: acc[i][j] has col(l15)=m within a[i], row(g*4+r)=n within b[j]
      #pragma unroll
      for (int kb = 0; kb < 2; ++kb) {
        short8 a[4], b[4];
        #pragma unroll
        for (int i = 0; i < 4; ++i) a[i] = fragr(As, wr*64 + i*16 + l15, kb*4 + g);
        #pragma unroll
        for (int j = 0; j < 4; ++j) b[j] = fragr(Bs, wc*64 + j*16 + l15, kb*4 + g);
        #pragma unroll
        for (int i = 0; i < 4; ++i)
          #pragma unroll
          for (int j = 0; j < 4; ++j)
            acc[i][j] = mfma16(b[j], a[i], acc[i][j]);
      }
    } else {
      #pragma unroll
      for (int kb = 0; kb < 2; ++kb) {
        short8 a[4], b[4];
        #pragma unroll
        for (int i = 0; i < 4; ++i) a[i] = fragr(As, wr*64 + i*16 + l15, kb*4 + g);
        #pragma unroll
        for (int j = 0; j < 4; ++j) b[j] = fragr(Bs, wc*64 + j*16 + l15, kb*4 + g);
        #pragma unroll
        for (int i = 0; i < 4; ++i)
          #pragma unroll
          for (int j = 0; j < 4; ++j)
            acc[i][j] = mfma16(a[i], b[j], acc[i][j]);
      }
    }
    __syncthreads();
  }

  if (z < 2) {
    // ---- RoPE fully in-lane: lane holds (m, n0..n0+3) = two complete pairs ----
    #pragma unroll
    for (int i = 0; i < 4; ++i) {
      const float s_f = (float)((row0 + wr*64 + i*16 + l15) & (S_-1));
      #pragma unroll
      for (int j = 0; j < 4; ++j) {
        const int ng = col0 + wc*64 + j*16 + g*4;   // global col of reg 0 (even)
        const float invf0 = exp2f(ROPE2 * (float)(ng >> 1));
        const float invf1 = exp2f(ROPE2 * (float)((ng >> 1) + 1));
        float sn0, cs0, sn1, cs1;
        sincosf(s_f * invf0, &sn0, &cs0);
        sincosf(s_f * invf1, &sn1, &cs1);
        const float x0 = acc[i][j][0], x1 = acc[i][j][1];
        const float x2 = acc[i][j][2], x3 = acc[i][j][3];
        acc[i][j][0] = x0*cs0 - x1*sn0;  acc[i][j][1] = x1*cs0 + x0*sn0;
        acc[i][j][2] = x2*cs1 - x3*sn1;  acc[i][j][3] = x3*cs1 + x2*sn1;
      }
    }
    // ---- row-major restage: SM[128 m][128 n] u16, 8B-granule swizzle ----
    #pragma unroll
    for (int i = 0; i < 4; ++i) {
      const int m = wr*64 + i*16 + l15;
      #pragma unroll
      for (int j = 0; j < 4; ++j) {
        const int n0 = wc*64 + j*16 + g*4;
        ushort4 pk;
        pk.x = f2b(acc[i][j][0]); pk.y = f2b(acc[i][j][1]);
        pk.z = f2b(acc[i][j][2]); pk.w = f2b(acc[i][j][3]);
        *reinterpret_cast<ushort4*>(SM + m*128 + ((((n0 >> 2) ^ ((m & 7) << 2))) << 2)) = pk;
      }
    }
    __syncthreads();
    u16* Ob = (z == 0) ? Qh : Kh;
    #pragma unroll
    for (int it = 0; it < 8; ++it) {
      const int u = it*256 + t;
      const int row = u >> 4, sl = u & 15;
      uint4 v = *reinterpret_cast<const uint4*>(
          SM + row*128 + ((((sl << 1) ^ ((row & 7) << 2))) << 2));
      *reinterpret_cast<uint4*>(Ob + (size_t)(row0 + row)*H_ + col0 + sl*8) = v;
    }
  }

  if (z == 1) {
    // ---- transpose restage: SM[128 d][128 s] u16, 16B-granule swizzle ----
    __syncthreads();
    #pragma unroll
    for (int i = 0; i < 4; ++i) {
      const int m = wr*64 + i*16 + l15;          // s
      #pragma unroll
      for (int j = 0; j < 4; ++j) {
        #pragma unroll
        for (int r = 0; r < 4; ++r) {
          const int n = wc*64 + j*16 + g*4 + r;  // d
          SM[n*128 + ((((m >> 3) ^ (n & 7)) << 3) + (m & 7))] = f2b(acc[i][j][r]);
        }
      }
    }
    __syncthreads();
    #pragma unroll
    for (int it = 0; it < 8; ++it) {
      const int u = it*256 + t;
      const int d = u >> 4, sl = u & 15;
      uint4 v = *reinterpret_cast<const uint4*>(SM + d*128 + ((sl ^ (d & 7)) << 3));
      const int rg0 = row0 + sl*8;
      const int bb = rg0 >> 13, s0 = rg0 & (S_-1);
      *reinterpret_cast<uint4*>(KT + (((size_t)(bb*H_ + col0 + d)) << 13) + s0) = v;
    }
  }

  if (z == 2) {
    // ---- per-wave 64x64 transpose regions (natural frag pack along s) ----
    #pragma unroll
    for (int jb = 0; jb < 4; ++jb) {
      const int cl = jb*16 + l15;                // j (V output col)
      #pragma unroll
      for (int ib = 0; ib < 4; ++ib) {
        const int rl0 = ib*16 + g*4;             // s local
        u16* R = SM + wid*4096;
        ushort4 pk;
        pk.x = f2b(acc[ib][jb][0]); pk.y = f2b(acc[ib][jb][1]);
        pk.z = f2b(acc[ib][jb][2]); pk.w = f2b(acc[ib][jb][3]);
        *reinterpret_cast<ushort4*>(R + cl*64 + (rl0 ^ ((cl & 7) << 3))) = pk;
      }
    }
    __syncthreads();
    #pragma unroll
    for (int it = 0; it < 8; ++it) {
      const int u = it*256 + t;
      const int w = u >> 9, cl = (u >> 3) & 63, sl = u & 7;
      const int sp = sl ^ (cl & 7);
      uint4 v = *reinterpret_cast<const uint4*>(SM + w*4096 + cl*64 + sp*8);
      const int dg  = col0 + (w & 1)*64 + cl;
      const int rg0 = row0 + ((w >> 1))*64 + sl*8;
      const int bb = rg0 >> 13, s0 = rg0 & (S_-1);
      const size_t dst = ((size_t)(bb*H_ + dg) << 13) + s0;
      *reinterpret_cast<uint4*>(VT + dst) = v;
      const u16* pv = reinterpret_cast<const u16*>(&v);
      float wv = expf((float)(C_ - 1 - (s0 & (C_-1))) * LNG);
      u16 ow[8];
      #pragma unroll
      for (int j2 = 0; j2 < 8; ++j2) { ow[j2] = f2b(b2f(pv[j2]) * wv); wv *= INVG; }
      *reinterpret_cast<uint4*>(VTw + dst) = *reinterpret_cast<uint4*>(ow);
    }
  }
}

// ---------------- K2: chunk outer product Tt[b,c][j][i] = sum_m w(m) V[m][j] K[m][i] ----
__global__ __launch_bounds__(256) void chunk_outer(
    const u16* __restrict__ KT, const u16* __restrict__ VTw, u16* __restrict__ Tt)
{
  __shared__ u16 SM[16384];
  const int t = threadIdx.x, l = t & 63, wid = t >> 6;
  const int wr = wid >> 1, wc = wid & 1, g = l >> 4, l15 = l & 15;
  const int c = blockIdx.x, b = blockIdx.y, q = blockIdx.z;
  const int j0 = (q >> 1) * 128, i0 = (q & 1) * 128;
  u16* As = SM; u16* Bs = SM + 8192;
  f32x4 acc[4][4] = {};

  for (int ks = 0; ks < 2; ++ks) {
    stageB(VTw + ((size_t)(b*H_ + j0) << 13) + c*C_ + ks*64, S_, As, t);
    stageB(KT  + ((size_t)(b*H_ + i0) << 13) + c*C_ + ks*64, S_, Bs, t);
    __syncthreads();
    #pragma unroll
    for (int kb = 0; kb < 2; ++kb) {
      short8 a[4], bb[4];
      #pragma unroll
      for (int i = 0; i < 4; ++i) a[i] = fragr(As, wr*64 + i*16 + l15, kb*4 + g);
      #pragma unroll
      for (int j = 0; j < 4; ++j) bb[j] = fragr(Bs, wc*64 + j*16 + l15, kb*4 + g);
      #pragma unroll
      for (int i = 0; i < 4; ++i)
        #pragma unroll
        for (int j = 0; j < 4; ++j)
          acc[i][j] = mfma16(a[i], bb[j], acc[i][j]);
    }
    __syncthreads();
  }
  const size_t tb = ((size_t)(b*NC_ + c)) << 16;
  #pragma unroll
  for (int jb = 0; jb < 4; ++jb) {
    const int i = i0 + wc*64 + jb*16 + l15;
    #pragma unroll
    for (int ib = 0; ib < 4; ++ib) {
      #pragma unroll
      for (int r = 0; r < 4; ++r) {
        const int j = j0 + wr*64 + ib*16 + g*4 + r;
        Tt[tb + (size_t)j*H_ + i] = f2b(acc[ib][jb][r]);
      }
    }
  }
}

// ---------------- K3: in-place exclusive scan: state[c] = g^C state[c-1] + T[c-1] ----
__global__ __launch_bounds__(256) void scan_state(u16* __restrict__ Tt)
{
  const unsigned e = blockIdx.x*256u + threadIdx.x;   // B_*65536 threads
  const unsigned b = e >> 16, el = e & 65535u;
  const float gC = expf((float)C_ * LNG);
  float run = 0.f;
  size_t p = (((size_t)b * NC_) << 16) + el;
  for (int c = 0; c < NC_; ++c, p += 65536) {
    const float tv = b2f(Tt[p]);
    Tt[p] = f2b(run);
    run = fmaf(gC, run, tv);
  }
}

// ---------------- K4: per-chunk output via MFMA ----------------
__global__ __launch_bounds__(256) void retention_out(
    const u16* __restrict__ Qh, const u16* __restrict__ Kh,
    const u16* __restrict__ VT, const u16* __restrict__ Tt,
    float* __restrict__ Out)
{
  __shared__ u16 SM[32768];   // 64KB: Sc [0,16384) u16, StA [16384,24576), StB [24576,32768)
  const int t = threadIdx.x, l = t & 63, wid = t >> 6;
  const int g = l >> 4, l15 = l & 15;
  const int c = blockIdx.x, b = blockIdx.y;
  u16* Sc = SM; u16* StA = SM + 16384; u16* StB = SM + 24576;
  const size_t chunkrow = ((size_t)(b*S_ + c*C_)) << 8;   // * H_

  // ---- phase 1: St[m][n] = sum_d K[m,d] Q[n,d]; mask+decay -> Sc[n][m] (swizzled) ----
  {
    const int m0w = (wid >> 1)*64, n0w = (wid & 1)*64;
    f32x4 acc[4][4] = {};
    for (int ks = 0; ks < 4; ++ks) {
      stageB(Kh + chunkrow + ks*64, H_, StA, t);
      stageB(Qh + chunkrow + ks*64, H_, StB, t);
      __syncthreads();
      #pragma unroll
      for (int kb = 0; kb < 2; ++kb) {
        short8 a[4], bb[4];
        #pragma unroll
        for (int i = 0; i < 4; ++i) a[i] = fragr(StA, m0w + i*16 + l15, kb*4 + g);
        #pragma unroll
        for (int j = 0; j < 4; ++j) bb[j] = fragr(StB, n0w + j*16 + l15, kb*4 + g);
        #pragma unroll
        for (int i = 0; i < 4; ++i)
          #pragma unroll
          for (int j = 0; j < 4; ++j)
            acc[i][j] = mfma16(a[i], bb[j], acc[i][j]);
      }
      __syncthreads();
    }
    #pragma unroll
    for (int jb = 0; jb < 4; ++jb) {
      const int n = n0w + jb*16 + l15;
      #pragma unroll
      for (int ib = 0; ib < 4; ++ib) {
        const int m0 = m0w + ib*16 + g*4;
        ushort4 pk;
        #pragma unroll
        for (int r = 0; r < 4; ++r) {
          const int m = m0 + r;
          const float sv = (n >= m) ? acc[ib][jb][r] * expf((float)(n - m)*LNG) : 0.f;
          reinterpret_cast<u16*>(&pk)[r] = f2b(sv);
        }
        *reinterpret_cast<ushort4*>(Sc + n*128 + (m0 ^ ((n & 15) << 3))) = pk;
      }
    }
  }
  __syncthreads();

  // ---- phase 2: D[j][n] = gamma^(n+1) * (Q @ state)^T + (S V)^T ----
  const int j0w = (wid >> 1)*64, n0w = (wid & 1)*64;
  const size_t sbase = ((size_t)(b*NC_ + c)) << 16;
  for (int h = 0; h < 2; ++h) {
    f32x4 acc[4][4] = {};
    // cross: contraction over d (4 ksteps)
    for (int ks = 0; ks < 4; ++ks) {
      stageB(Tt + sbase + (size_t)(h*128)*H_ + ks*64, H_, StA, t);
      stageB(Qh + chunkrow + ks*64, H_, StB, t);
      __syncthreads();
      #pragma unroll
      for (int kb = 0; kb < 2; ++kb) {
        short8 a[4], bb[4];
        #pragma unroll
        for (int i = 0; i < 4; ++i) a[i] = fragr(StA, j0w + i*16 + l15, kb*4 + g);
        #pragma unroll
        for (int j = 0; j < 4; ++j) bb[j] = fragr(StB, n0w + j*16 + l15, kb*4 + g);
        #pragma unroll
        for (int i = 0; i < 4; ++i)
          #pragma unroll
          for (int j = 0; j < 4; ++j)
            acc[i][j] = mfma16(a[i], bb[j], acc[i][j]);
      }
      __syncthreads();
    }
    // scale cross by gamma^(n+1)
    #pragma unroll
    for (int jb = 0; jb < 4; ++jb) {
      const float gn = expf((float)(n0w + jb*16 + l15 + 1) * LNG);
      #pragma unroll
      for (int ib = 0; ib < 4; ++ib)
        #pragma unroll
        for (int r = 0; r < 4; ++r) acc[ib][jb][r] *= gn;
    }
    // local: contraction over m (2 ksteps), B from Sc
    for (int ks2 = 0; ks2 < 2; ++ks2) {
      stageB(VT + ((size_t)(b*H_ + h*128) << 13) + c*C_ + ks2*64, S_, StA, t);
      __syncthreads();
      #pragma unroll
      for (int kb = 0; kb < 2; ++kb) {
        short8 a[4], bb[4];
        #pragma unroll
        for (int i = 0; i < 4; ++i) a[i] = fragr(StA, j0w + i*16 + l15, kb*4 + g);
        #pragma unroll
        for (int j = 0; j < 4; ++j) {
          const int n = n0w + j*16 + l15;
          bb[j] = *reinterpret_cast<const short8*>(
              Sc + n*128 + (((ks2*8 + kb*4 + g) ^ (n & 15)) << 3));
        }
        #pragma unroll
        for (int i = 0; i < 4; ++i)
          #pragma unroll
          for (int j = 0; j < 4; ++j)
            acc[i][j] = mfma16(a[i], bb[j], acc[i][j]);
      }
      __syncthreads();
    }
    // epilogue: restage [64 n][128 j] f32 in LDS (swizzled), coalesced global store
    float* OL = reinterpret_cast<float*>(SM + 16384);   // 32KB region
    for (int ph = 0; ph < 2; ++ph) {
      if ((wid & 1) == ph) {
        #pragma unroll
        for (int jb = 0; jb < 4; ++jb) {
          const int nl = jb*16 + l15;
          #pragma unroll
          for (int ib = 0; ib < 4; ++ib) {
            const int jl = j0w + ib*16 + g*4;
            *reinterpret_cast<f32x4*>(OL + nl*128 + (jl ^ ((nl & 15) << 2))) = acc[ib][jb];
          }
        }
      }
      __syncthreads();
      #pragma unroll
      for (int it = 0; it < 8; ++it) {
        const int u = it*256 + t;
        const int nl = u >> 5, sl = u & 31;
        f32x4 v = *reinterpret_cast<const f32x4*>(OL + nl*128 + ((sl ^ (nl & 15)) << 2));
        const int n = c*C_ + ph*64 + nl;
        *reinterpret_cast<f32x4*>(Out + (((size_t)(b*S_ + n)) << 8) + h*128 + sl*4) = v;
      }
      __syncthreads();
    }
  }
}

extern "C" void kernel_launch(void* const* d_in, const int* in_sizes, int n_in,
                              void* d_out, int out_size, void* d_ws, size_t ws_size,
                              hipStream_t stream) {
  const float* X  = (const float*)d_in[0];
  const float* Wq = (const float*)d_in[1];
  const float* Wk = (const float*)d_in[2];
  const float* Wv = (const float*)d_in[3];
  float* Out = (float*)d_out;
  u16* ws = (u16*)d_ws;
  // workspace (u16 elems): WhT 196608 | Qh,Kh,KT,VT,VTw 8388608 each | Tt 16777216  (~118 MB)
  u16* WhT = ws;
  u16* Qh  = WhT + 196608;
  u16* Kh  = Qh  + (size_t)M_*H_;
  u16* KT  = Kh  + (size_t)M_*H_;
  u16* VT  = KT  + (size_t)M_*H_;
  u16* VTw = VT  + (size_t)M_*H_;
  u16* Tt  = VTw + (size_t)M_*H_;

  convert_w<<<96, 256, 0, stream>>>(Wq, Wk, Wv, WhT);
  gemm_qkv<<<dim3(M_/128, H_/128, 3), 256, 0, stream>>>(X, WhT, Qh, Kh, KT, VT, VTw);
  chunk_outer<<<dim3(NC_, B_, 4), 256, 0, stream>>>(KT, VTw, Tt);
  scan_state<<<(B_*H_*H_)/256, 256, 0, stream>>>(Tt);
  retention_out<<<dim3(NC_, B_), 256, 0, stream>>>(Qh, Kh, VT, Tt, Out);
}

// Round 4
// 115.368 us; speedup vs baseline: 3.7179x; 1.1672x over previous
//
#include <hip/hip_runtime.h>
#include <hip/hip_bf16.h>

#define B_  4
#define S_  8192
#define H_  256
#define C_  128
#define NC_ 64
#define M_  (B_*S_)

typedef unsigned short u16;
typedef __attribute__((ext_vector_type(8))) short short8;
typedef __attribute__((ext_vector_type(4))) float f32x4;
typedef __attribute__((address_space(1))) void gas_t;
typedef __attribute__((address_space(3))) void las_t;

static constexpr float LNG   = -0.031748698f;          // ln(0.96875)
static constexpr float ROPE2 = -0.103810253f;          // -(2/256)*log2(10000)
static constexpr float I2PI  = 0.15915494f;            // 1/(2*pi)

__device__ __forceinline__ u16 f2b(float x) {
  union { __hip_bfloat16 b; u16 u; } c; c.b = __float2bfloat16(x); return c.u;
}
__device__ __forceinline__ float b2f(u16 u) {
  union { u16 u; __hip_bfloat16 b; } c; c.u = u; return __bfloat162float(c.b);
}
__device__ __forceinline__ f32x4 mfma16(short8 a, short8 b, f32x4 c) {
  return __builtin_amdgcn_mfma_f32_16x16x32_bf16(a, b, c, 0, 0, 0);
}

// ---- swizzled [128 rows][64 cols] bf16 tile; phys 16B-slot = slot ^ (row&7) ----
__device__ __forceinline__ void stageB(const u16* __restrict__ src, int stride,
                                       u16* lds, int t) {
  #pragma unroll
  for (int it = 0; it < 4; ++it) {
    const int u = it*256 + t, row = u >> 3, sl = u & 7, lsl = sl ^ (row & 7);
    uint4 v = *reinterpret_cast<const uint4*>(src + (size_t)row*stride + lsl*8);
    *reinterpret_cast<uint4*>(lds + u*8) = v;
  }
}
// async variant: direct-to-LDS, pre-swizzled global source, linear LDS dest
__device__ __forceinline__ void stageA(const u16* __restrict__ src, int stride,
                                       u16* smbase, int off, int t) {
  #pragma unroll
  for (int it = 0; it < 4; ++it) {
    const int u = it*256 + t, row = u >> 3, lsl = (u & 7) ^ (row & 7);
    const u16* gp = src + (size_t)row*stride + lsl*8;
    u16* lp = smbase + off + it*2048 + (t & 192)*8;   // wave-uniform base
    __builtin_amdgcn_global_load_lds((gas_t*)gp, (las_t*)lp, 16, 0, 0);
  }
}
__device__ __forceinline__ short8 fragr(const u16* lds, int row, int slot) {
  return *reinterpret_cast<const short8*>(lds + row*64 + ((slot ^ (row & 7)) << 3));
}

// ---------------- K0: prep — X -> bf16, W -> transposed bf16 ----------------
__global__ __launch_bounds__(256) void prep(
    const float* __restrict__ X, const float* __restrict__ Wq,
    const float* __restrict__ Wk, const float* __restrict__ Wv,
    u16* __restrict__ Xh, u16* __restrict__ WhT)
{
  const int bid = blockIdx.x;
  if (bid < 96) {   // W transpose: 24576 threads, 8 elems each
    const int i = bid*256 + threadIdx.x;
    const int z = i >> 13, r = i & 8191;
    const int n = r >> 5, k0 = (r & 31) << 3;
    const float* W = (z == 0) ? Wq : (z == 1) ? Wk : Wv;
    u16 o[8];
    #pragma unroll
    for (int j = 0; j < 8; ++j) o[j] = f2b(W[(size_t)(k0 + j)*H_ + n]);
    *reinterpret_cast<uint4*>(WhT + ((size_t)z << 16) + n*H_ + k0) =
        *reinterpret_cast<uint4*>(o);
    return;
  }
  const int j = (bid - 96)*256 + threadIdx.x;   // 0..1048575, 8 elems each
  const float* p = X + (size_t)j*8;
  float4 a = *reinterpret_cast<const float4*>(p);
  float4 b = *reinterpret_cast<const float4*>(p + 4);
  u16 o[8] = {f2b(a.x), f2b(a.y), f2b(a.z), f2b(a.w),
              f2b(b.x), f2b(b.y), f2b(b.z), f2b(b.w)};
  *reinterpret_cast<uint4*>(Xh + (size_t)j*8) = *reinterpret_cast<uint4*>(o);
}

// ---------------- K1: fused QKV projection + RoPE + transposes ----------------
// z=0: Qh row-major (swapped mfma). z=1: Kh row-major + KT[b][d][s] (swapped mfma).
// z=2: VT[b][j][s] + VTw decay-weighted (normal mfma).
__global__ __launch_bounds__(256) void gemm_qkv(
    const u16* __restrict__ Xh, const u16* __restrict__ WhT,
    u16* __restrict__ Qh, u16* __restrict__ Kh,
    u16* __restrict__ KT, u16* __restrict__ VT, u16* __restrict__ VTw)
{
  __shared__ u16 SM[32768];   // 64KB: dbuf {A0,B0,A1,B1}x16KB; epilogue reuses [0,16384)
  const int t = threadIdx.x, l = t & 63, wid = t >> 6;
  const int wr = wid >> 1, wc = wid & 1, g = l >> 4, l15 = l & 15;
  const int z = blockIdx.z;
  const int row0 = blockIdx.x * 128, col0 = blockIdx.y * 128;
  const u16* Asrc = Xh + (size_t)row0*H_;
  const u16* Bsrc = WhT + ((size_t)z << 16) + (size_t)col0*H_;
  f32x4 acc[4][4] = {};

  stageA(Asrc, H_, SM, 0, t);
  stageA(Bsrc, H_, SM, 8192, t);
  __syncthreads();
  for (int ks = 0; ks < 4; ++ks) {
    const int cur = (ks & 1) * 16384;
    if (ks < 3) {
      stageA(Asrc + (ks+1)*64, H_, SM, 16384 - cur, t);
      stageA(Bsrc + (ks+1)*64, H_, SM, 16384 - cur + 8192, t);
    }
    const u16* As = SM + cur;
    const u16* Bs = SM + cur + 8192;
    #pragma unroll
    for (int kb = 0; kb < 2; ++kb) {
      short8 a[4], b[4];
      #pragma unroll
      for (int i = 0; i < 4; ++i) a[i] = fragr(As, wr*64 + i*16 + l15, kb*4 + g);
      #pragma unroll
      for (int j = 0; j < 4; ++j) b[j] = fragr(Bs, wc*64 + j*16 + l15, kb*4 + g);
      if (z < 2) {
        #pragma unroll
        for (int i = 0; i < 4; ++i)
          #pragma unroll
          for (int j = 0; j < 4; ++j)
            acc[i][j] = mfma16(b[j], a[i], acc[i][j]);   // swapped: l15=m, regs=n
      } else {
        #pragma unroll
        for (int i = 0; i < 4; ++i)
          #pragma unroll
          for (int j = 0; j < 4; ++j)
            acc[i][j] = mfma16(a[i], b[j], acc[i][j]);
      }
    }
    __syncthreads();
  }

  if (z < 2) {
    // ---- RoPE fully in-lane via hw trig: lane holds (m, n0..n0+3) = 2 pairs ----
    #pragma unroll
    for (int i = 0; i < 4; ++i) {
      const float s_f = (float)((row0 + wr*64 + i*16 + l15) & (S_-1));
      #pragma unroll
      for (int j = 0; j < 4; ++j) {
        const int ng = col0 + wc*64 + j*16 + g*4;
        const float h0 = (float)(ng >> 1);
        float rv0 = s_f * (exp2f(ROPE2 * h0) * I2PI);
        float rv1 = s_f * (exp2f(ROPE2 * (h0 + 1.0f)) * I2PI);
        rv0 -= floorf(rv0);  rv1 -= floorf(rv1);
        const float sn0 = __builtin_amdgcn_sinf(rv0), cs0 = __builtin_amdgcn_cosf(rv0);
        const float sn1 = __builtin_amdgcn_sinf(rv1), cs1 = __builtin_amdgcn_cosf(rv1);
        const float x0 = acc[i][j][0], x1 = acc[i][j][1];
        const float x2 = acc[i][j][2], x3 = acc[i][j][3];
        acc[i][j][0] = x0*cs0 - x1*sn0;  acc[i][j][1] = x1*cs0 + x0*sn0;
        acc[i][j][2] = x2*cs1 - x3*sn1;  acc[i][j][3] = x3*cs1 + x2*sn1;
      }
    }
    // ---- row-major restage: SM[128 m][128 n] u16, 8B-granule swizzle ----
    #pragma unroll
    for (int i = 0; i < 4; ++i) {
      const int m = wr*64 + i*16 + l15;
      #pragma unroll
      for (int j = 0; j < 4; ++j) {
        const int n0 = wc*64 + j*16 + g*4;
        ushort4 pk;
        pk.x = f2b(acc[i][j][0]); pk.y = f2b(acc[i][j][1]);
        pk.z = f2b(acc[i][j][2]); pk.w = f2b(acc[i][j][3]);
        *reinterpret_cast<ushort4*>(SM + m*128 + ((((n0 >> 2) ^ ((m & 7) << 2))) << 2)) = pk;
      }
    }
    __syncthreads();
    u16* Ob = (z == 0) ? Qh : Kh;
    #pragma unroll
    for (int it = 0; it < 8; ++it) {
      const int u = it*256 + t;
      const int row = u >> 4, sl = u & 15;
      uint4 v = *reinterpret_cast<const uint4*>(
          SM + row*128 + ((((sl << 1) ^ ((row & 7) << 2))) << 2));
      *reinterpret_cast<uint4*>(Ob + (size_t)(row0 + row)*H_ + col0 + sl*8) = v;
    }
  }

  if (z == 1) {
    // ---- transpose restage: SM[128 d][128 s] u16, 8-granule swizzle ----
    __syncthreads();
    #pragma unroll
    for (int i = 0; i < 4; ++i) {
      const int m = wr*64 + i*16 + l15;          // s
      #pragma unroll
      for (int j = 0; j < 4; ++j) {
        #pragma unroll
        for (int r = 0; r < 4; ++r) {
          const int n = wc*64 + j*16 + g*4 + r;  // d
          SM[n*128 + ((((m >> 3) ^ (n & 7)) << 3) + (m & 7))] = f2b(acc[i][j][r]);
        }
      }
    }
    __syncthreads();
    #pragma unroll
    for (int it = 0; it < 8; ++it) {
      const int u = it*256 + t;
      const int d = u >> 4, sl = u & 15;
      uint4 v = *reinterpret_cast<const uint4*>(SM + d*128 + ((sl ^ (d & 7)) << 3));
      const int rg0 = row0 + sl*8;
      const int bb = rg0 >> 13, s0 = rg0 & (S_-1);
      *reinterpret_cast<uint4*>(KT + (((size_t)(bb*H_ + col0 + d)) << 13) + s0) = v;
    }
  }

  if (z == 2) {
    // ---- per-wave 64x64 transpose regions (natural frag pack along s) ----
    #pragma unroll
    for (int jb = 0; jb < 4; ++jb) {
      const int cl = jb*16 + l15;                // j (V output col)
      #pragma unroll
      for (int ib = 0; ib < 4; ++ib) {
        const int rl0 = ib*16 + g*4;             // s local
        u16* R = SM + wid*4096;
        ushort4 pk;
        pk.x = f2b(acc[ib][jb][0]); pk.y = f2b(acc[ib][jb][1]);
        pk.z = f2b(acc[ib][jb][2]); pk.w = f2b(acc[ib][jb][3]);
        *reinterpret_cast<ushort4*>(R + cl*64 + (rl0 ^ ((cl & 7) << 3))) = pk;
      }
    }
    __syncthreads();
    #pragma unroll
    for (int it = 0; it < 8; ++it) {
      const int u = it*256 + t;
      const int w = u >> 9, cl = (u >> 3) & 63, sl = u & 7;
      const int sp = sl ^ (cl & 7);
      uint4 v = *reinterpret_cast<const uint4*>(SM + w*4096 + cl*64 + sp*8);
      const int dg  = col0 + (w & 1)*64 + cl;
      const int rg0 = row0 + ((w >> 1))*64 + sl*8;
      const int bb = rg0 >> 13, s0 = rg0 & (S_-1);
      const size_t dst = ((size_t)(bb*H_ + dg) << 13) + s0;
      *reinterpret_cast<uint4*>(VT + dst) = v;
      const u16* pv = reinterpret_cast<const u16*>(&v);
      u16 ow[8];
      #pragma unroll
      for (int j2 = 0; j2 < 8; ++j2) {
        const float wv = expf((float)(C_ - 1 - ((s0 + j2) & (C_-1))) * LNG);
        ow[j2] = f2b(b2f(pv[j2]) * wv);
      }
      *reinterpret_cast<uint4*>(VTw + dst) = *reinterpret_cast<uint4*>(ow);
    }
  }
}

// ---------------- K2: chunk outer product Tt[b,c][j][i] = sum_m w(m) V[m][j] K[m][i] ----
__global__ __launch_bounds__(256) void chunk_outer(
    const u16* __restrict__ KT, const u16* __restrict__ VTw, u16* __restrict__ Tt)
{
  __shared__ u16 SM[32768];   // 64KB dbuf; epilogue reuses [0,16384)
  const int t = threadIdx.x, l = t & 63, wid = t >> 6;
  const int wr = wid >> 1, wc = wid & 1, g = l >> 4, l15 = l & 15;
  const int c = blockIdx.x, b = blockIdx.y, q = blockIdx.z;
  const int j0 = (q >> 1) * 128, i0 = (q & 1) * 128;
  const u16* Asrc = VTw + ((size_t)(b*H_ + j0) << 13) + c*C_;
  const u16* Bsrc = KT  + ((size_t)(b*H_ + i0) << 13) + c*C_;
  f32x4 acc[4][4] = {};

  stageA(Asrc, S_, SM, 0, t);
  stageA(Bsrc, S_, SM, 8192, t);
  __syncthreads();
  for (int ks = 0; ks < 2; ++ks) {
    const int cur = (ks & 1) * 16384;
    if (ks < 1) {
      stageA(Asrc + 64, S_, SM, 16384, t);
      stageA(Bsrc + 64, S_, SM, 16384 + 8192, t);
    }
    const u16* As = SM + cur;
    const u16* Bs = SM + cur + 8192;
    #pragma unroll
    for (int kb = 0; kb < 2; ++kb) {
      short8 a[4], bb[4];
      #pragma unroll
      for (int i = 0; i < 4; ++i) a[i] = fragr(As, wr*64 + i*16 + l15, kb*4 + g);
      #pragma unroll
      for (int j = 0; j < 4; ++j) bb[j] = fragr(Bs, wc*64 + j*16 + l15, kb*4 + g);
      #pragma unroll
      for (int i = 0; i < 4; ++i)
        #pragma unroll
        for (int j = 0; j < 4; ++j)
          acc[i][j] = mfma16(a[i], bb[j], acc[i][j]);
    }
    __syncthreads();
  }
  // restage [128 j][128 i] u16 with 8-granule swizzle, coalesced store
  #pragma unroll
  for (int jb = 0; jb < 4; ++jb) {
    const int il = wc*64 + jb*16 + l15;
    #pragma unroll
    for (int ib = 0; ib < 4; ++ib) {
      #pragma unroll
      for (int r = 0; r < 4; ++r) {
        const int jl = wr*64 + ib*16 + g*4 + r;
        SM[jl*128 + ((((il >> 3) ^ (jl & 7)) << 3) + (il & 7))] = f2b(acc[ib][jb][r]);
      }
    }
  }
  __syncthreads();
  const size_t tb = ((size_t)(b*NC_ + c)) << 16;
  #pragma unroll
  for (int it = 0; it < 8; ++it) {
    const int u = it*256 + t;
    const int jl = u >> 4, sl = u & 15;
    uint4 v = *reinterpret_cast<const uint4*>(SM + jl*128 + ((sl ^ (jl & 7)) << 3));
    *reinterpret_cast<uint4*>(Tt + tb + (size_t)(j0 + jl)*H_ + i0 + sl*8) = v;
  }
}

// ---------------- K3: in-place exclusive scan: state[c] = g^C state[c-1] + T[c-1] ----
__global__ __launch_bounds__(256) void scan_state(u16* __restrict__ Tt)
{
  const unsigned e = blockIdx.x*256u + threadIdx.x;   // B_*16384 threads, 4 elems each
  const unsigned b = e >> 14, el = (e & 16383u) << 2;
  const float gC = expf((float)C_ * LNG);
  float r0 = 0.f, r1 = 0.f, r2 = 0.f, r3 = 0.f;
  size_t p = (((size_t)b * NC_) << 16) + el;
  for (int c = 0; c < NC_; ++c, p += 65536) {
    uint2 v = *reinterpret_cast<uint2*>(Tt + p);
    const float t0 = b2f((u16)(v.x & 0xffff)), t1 = b2f((u16)(v.x >> 16));
    const float t2 = b2f((u16)(v.y & 0xffff)), t3 = b2f((u16)(v.y >> 16));
    uint2 o;
    o.x = (unsigned)f2b(r0) | ((unsigned)f2b(r1) << 16);
    o.y = (unsigned)f2b(r2) | ((unsigned)f2b(r3) << 16);
    *reinterpret_cast<uint2*>(Tt + p) = o;
    r0 = fmaf(gC, r0, t0); r1 = fmaf(gC, r1, t1);
    r2 = fmaf(gC, r2, t2); r3 = fmaf(gC, r3, t3);
  }
}

// ---------------- K4: per-chunk output via MFMA ----------------
__global__ __launch_bounds__(256) void retention_out(
    const u16* __restrict__ Qh, const u16* __restrict__ Kh,
    const u16* __restrict__ VT, const u16* __restrict__ Tt,
    float* __restrict__ Out)
{
  __shared__ u16 SM[32768];   // 64KB: Sc [0,16384), StA [16384,24576), StB [24576,32768)
  const int t = threadIdx.x, l = t & 63, wid = t >> 6;
  const int g = l >> 4, l15 = l & 15;
  const int c = blockIdx.x, b = blockIdx.y;
  u16* Sc = SM; u16* StA = SM + 16384; u16* StB = SM + 24576;
  const size_t chunkrow = ((size_t)(b*S_ + c*C_)) << 8;   // * H_

  // ---- phase 1: St[m][n] = sum_d K[m,d] Q[n,d]; mask+decay -> Sc[n][m] (swizzled) ----
  {
    const int m0w = (wid >> 1)*64, n0w = (wid & 1)*64;
    f32x4 acc[4][4] = {};
    for (int ks = 0; ks < 4; ++ks) {
      stageB(Kh + chunkrow + ks*64, H_, StA, t);
      stageB(Qh + chunkrow + ks*64, H_, StB, t);
      __syncthreads();
      #pragma unroll
      for (int kb = 0; kb < 2; ++kb) {
        short8 a[4], bb[4];
        #pragma unroll
        for (int i = 0; i < 4; ++i) a[i] = fragr(StA, m0w + i*16 + l15, kb*4 + g);
        #pragma unroll
        for (int j = 0; j < 4; ++j) bb[j] = fragr(StB, n0w + j*16 + l15, kb*4 + g);
        #pragma unroll
        for (int i = 0; i < 4; ++i)
          #pragma unroll
          for (int j = 0; j < 4; ++j)
            acc[i][j] = mfma16(a[i], bb[j], acc[i][j]);
      }
      __syncthreads();
    }
    #pragma unroll
    for (int jb = 0; jb < 4; ++jb) {
      const int n = n0w + jb*16 + l15;
      #pragma unroll
      for (int ib = 0; ib < 4; ++ib) {
        const int m0 = m0w + ib*16 + g*4;
        ushort4 pk;
        #pragma unroll
        for (int r = 0; r < 4; ++r) {
          const int m = m0 + r;
          const float sv = (n >= m) ? acc[ib][jb][r] * expf((float)(n - m)*LNG) : 0.f;
          reinterpret_cast<u16*>(&pk)[r] = f2b(sv);
        }
        *reinterpret_cast<ushort4*>(Sc + n*128 + (m0 ^ ((n & 15) << 3))) = pk;
      }
    }
  }
  __syncthreads();

  // ---- phase 2: D[j][n] = gamma^(n+1) * (Q @ state)^T + (S V)^T ----
  const int j0w = (wid >> 1)*64, n0w = (wid & 1)*64;
  const size_t sbase = ((size_t)(b*NC_ + c)) << 16;
  for (int h = 0; h < 2; ++h) {
    const int j0 = h*128;
    f32x4 acc[4][4] = {};
    // cross: contraction over d (4 ksteps)
    for (int ks = 0; ks < 4; ++ks) {
      stageB(Tt + sbase + (size_t)j0*H_ + ks*64, H_, StA, t);
      stageB(Qh + chunkrow + ks*64, H_, StB, t);
      __syncthreads();
      #pragma unroll
      for (int kb = 0; kb < 2; ++kb) {
        short8 a[4], bb[4];
        #pragma unroll
        for (int i = 0; i < 4; ++i) a[i] = fragr(StA, j0w + i*16 + l15, kb*4 + g);
        #pragma unroll
        for (int j = 0; j < 4; ++j) bb[j] = fragr(StB, n0w + j*16 + l15, kb*4 + g);
        #pragma unroll
        for (int i = 0; i < 4; ++i)
          #pragma unroll
          for (int j = 0; j < 4; ++j)
            acc[i][j] = mfma16(a[i], bb[j], acc[i][j]);
      }
      __syncthreads();
    }
    // scale cross by gamma^(n+1)
    #pragma unroll
    for (int jb = 0; jb < 4; ++jb) {
      const float gn = expf((float)(n0w + jb*16 + l15 + 1) * LNG);
      #pragma unroll
      for (int ib = 0; ib < 4; ++ib)
        #pragma unroll
        for (int r = 0; r < 4; ++r) acc[ib][jb][r] *= gn;
    }
    // local: contraction over m (2 ksteps), B from Sc
    for (int ks2 = 0; ks2 < 2; ++ks2) {
      stageB(VT + ((size_t)(b*H_ + j0) << 13) + c*C_ + ks2*64, S_, StA, t);
      __syncthreads();
      #pragma unroll
      for (int kb = 0; kb < 2; ++kb) {
        short8 a[4], bb[4];
        #pragma unroll
        for (int i = 0; i < 4; ++i) a[i] = fragr(StA, j0w + i*16 + l15, kb*4 + g);
        #pragma unroll
        for (int j = 0; j < 4; ++j) {
          const int n = n0w + j*16 + l15;
          bb[j] = *reinterpret_cast<const short8*>(
              Sc + n*128 + (((ks2*8 + kb*4 + g) ^ (n & 15)) << 3));
        }
        #pragma unroll
        for (int i = 0; i < 4; ++i)
          #pragma unroll
          for (int j = 0; j < 4; ++j)
            acc[i][j] = mfma16(a[i], bb[j], acc[i][j]);
      }
      __syncthreads();
    }
    // epilogue: restage [64 n][128 j] f32 in LDS (swizzled), coalesced global store
    float* OL = reinterpret_cast<float*>(SM + 16384);   // 32KB region
    for (int ph = 0; ph < 2; ++ph) {
      if ((wid & 1) == ph) {
        #pragma unroll
        for (int jb = 0; jb < 4; ++jb) {
          const int nl = jb*16 + l15;
          #pragma unroll
          for (int ib = 0; ib < 4; ++ib) {
            const int jl = j0w + ib*16 + g*4;
            *reinterpret_cast<f32x4*>(OL + nl*128 + (jl ^ ((nl & 15) << 2))) = acc[ib][jb];
          }
        }
      }
      __syncthreads();
      #pragma unroll
      for (int it = 0; it < 8; ++it) {
        const int u = it*256 + t;
        const int nl = u >> 5, sl = u & 31;
        f32x4 v = *reinterpret_cast<const f32x4*>(OL + nl*128 + ((sl ^ (nl & 15)) << 2));
        const int n = c*C_ + ph*64 + nl;
        *reinterpret_cast<f32x4*>(Out + (((size_t)(b*S_ + n)) << 8) + j0 + sl*4) = v;
      }
      __syncthreads();
    }
  }
}

extern "C" void kernel_launch(void* const* d_in, const int* in_sizes, int n_in,
                              void* d_out, int out_size, void* d_ws, size_t ws_size,
                              hipStream_t stream) {
  const float* X  = (const float*)d_in[0];
  const float* Wq = (const float*)d_in[1];
  const float* Wk = (const float*)d_in[2];
  const float* Wv = (const float*)d_in[3];
  float* Out = (float*)d_out;
  u16* ws = (u16*)d_ws;
  // workspace (u16): WhT 196608 | Xh | Qh,Kh,KT,VT,VTw | Tt  (~135 MB)
  u16* WhT = ws;
  u16* Xh  = WhT + 196608;
  u16* Qh  = Xh  + (size_t)M_*H_;
  u16* Kh  = Qh  + (size_t)M_*H_;
  u16* KT  = Kh  + (size_t)M_*H_;
  u16* VT  = KT  + (size_t)M_*H_;
  u16* VTw = VT  + (size_t)M_*H_;
  u16* Tt  = VTw + (size_t)M_*H_;

  prep<<<96 + 4096, 256, 0, stream>>>(X, Wq, Wk, Wv, Xh, WhT);
  gemm_qkv<<<dim3(M_/128, H_/128, 3), 256, 0, stream>>>(Xh, WhT, Qh, Kh, KT, VT, VTw);
  chunk_outer<<<dim3(NC_, B_, 4), 256, 0, stream>>>(KT, VTw, Tt);
  scan_state<<<(B_*H_*H_/4)/256, 256, 0, stream>>>(Tt);
  retention_out<<<dim3(NC_, B_), 256, 0, stream>>>(Qh, Kh, VT, Tt, Out);
}